// Round 7
// baseline (259.905 us; speedup 1.0000x reference)
//
#include <hip/hip_runtime.h>

#define E_CNT 2000000
#define N_CNT 200000
#define B_CNT 100
#define R_CNT 13
#define G_CNT 512
#define T_CNT 10
#define OE_CNT 4

// fp16 fused table: P[b][g][32 halfs] = { h[13], pad3, o[13], pad3 } = 64 B row.
// Total = 100*512*64 B = 3.28 MB.  One edge needs rows idx, idx+1 = 128 B
// contiguous.
#define P_ROWH 32
#define P_HALFS ((size_t)B_CNT * G_CNT * P_ROWH)
#define P_BYTES (P_HALFS * 2)

// Main kernel geometry: 1 thread = 1 edge, 256 edges per block.
#define EPB 256
#define EDGE_BLOCKS ((E_CNT + EPB - 1) / EPB)       // 7813 (last block: 128 edges)
#define NODE_BLOCKS ((N_CNT + 255) / 256)           // 782
#define OUT_OVL_OFF ((size_t)E_CNT * R_CNT)
#define OUT_NODE_OFF ((size_t)2 * E_CNT * R_CNT)

#define SH_STRIDE 17                                 // odd -> conflict-free writes

typedef float v4f __attribute__((ext_vector_type(4)));
typedef _Float16 v8h __attribute__((ext_vector_type(8)));

// One thread per (b,g): coalesced fp32 source reads (lanes stride over g),
// one full 64 B fp16 row write.  Grid 200 blocks.
__global__ __launch_bounds__(256) void repack_h16_kernel(
    const float* __restrict__ hopping,
    const float* __restrict__ overlap,
    _Float16* __restrict__ P)
{
    int tid = blockIdx.x * 256 + threadIdx.x;       // 0..51199 = b*512+g
    int b = tid >> 9;
    int g = tid & (G_CNT - 1);
    float h[13], o[13];
    #pragma unroll
    for (int r = 0; r < R_CNT; ++r) {
        size_t src = (((size_t)b * R_CNT + r) << 9) + g;   // lanes: consecutive g
        h[r] = hopping[src];
        o[r] = overlap[src];
    }
    v8h w0, w1, w2, w3;
    #pragma unroll
    for (int k = 0; k < 8; ++k) {
        w0[k] = (_Float16)h[k];
        w1[k] = (8 + k < R_CNT) ? (_Float16)h[8 + k] : (_Float16)0.0f;
        w2[k] = (_Float16)o[k];
        w3[k] = (8 + k < R_CNT) ? (_Float16)o[8 + k] : (_Float16)0.0f;
    }
    _Float16* dst = P + (size_t)tid * P_ROWH;
    *(v8h*)(dst)      = w0;
    *(v8h*)(dst + 8)  = w1;
    *(v8h*)(dst + 16) = w2;
    *(v8h*)(dst + 24) = w3;
}

// 1 thread = 1 edge.  Each thread issues 8 independent 16 B loads covering the
// edge's full 128 B table span (rows idx & idx+1, h+o) -> 4x the per-thread
// memory-level parallelism of the previous 4-threads/edge scheme.
__global__ __launch_bounds__(256, 4) void sk16_mlp_kernel(
    const float* __restrict__ rij,
    const int*   __restrict__ edge_type,
    const _Float16* __restrict__ P,
    const int*   __restrict__ atom_type,
    const float* __restrict__ onsite,
    float* __restrict__ out)
{
    if (blockIdx.x < EDGE_BLOCKS) {
        __shared__ float shh[EPB * SH_STRIDE];
        __shared__ float sho[EPB * SH_STRIDE];

        int tid   = threadIdx.x;
        int ebase = blockIdx.x * EPB;
        int ne    = min(EPB, E_CNT - ebase);         // block-uniform (256 or 128)

        if (tid < ne) {
            int e = ebase + tid;
            float r = __builtin_nontemporal_load(rij + e);
            int   b = __builtin_nontemporal_load(edge_type + e);

            // xx = linspace(1,6,512): closed-form interval + fraction.
            const float inv_dx = 511.0f / 5.0f;
            float s = (r - 1.0f) * inv_dx;
            int idx = (int)s;
            idx = max(0, min(G_CNT - 2, idx));
            float t = s - (float)idx;
            float omt = 1.0f - t;

            // 8 independent loads, all issued before first use.
            const _Float16* rowp = P + ((size_t)((b << 9) + idx)) * P_ROWH;
            v8h a0 = *(const v8h*)(rowp);            // h[0..7]  @ idx
            v8h a1 = *(const v8h*)(rowp + 8);        // h[8..12] @ idx
            v8h a2 = *(const v8h*)(rowp + 16);       // o[0..7]  @ idx
            v8h a3 = *(const v8h*)(rowp + 24);       // o[8..12] @ idx
            v8h b0 = *(const v8h*)(rowp + 32);       // h[0..7]  @ idx+1
            v8h b1 = *(const v8h*)(rowp + 40);
            v8h b2 = *(const v8h*)(rowp + 48);
            v8h b3 = *(const v8h*)(rowp + 56);

            float* hrow = shh + tid * SH_STRIDE;
            float* orow = sho + tid * SH_STRIDE;
            #pragma unroll
            for (int k = 0; k < 8; ++k) hrow[k] = (float)a0[k] * omt + (float)b0[k] * t;
            #pragma unroll
            for (int k = 0; k < 5; ++k) hrow[8 + k] = (float)a1[k] * omt + (float)b1[k] * t;
            #pragma unroll
            for (int k = 0; k < 8; ++k) orow[k] = (float)a2[k] * omt + (float)b2[k] * t;
            #pragma unroll
            for (int k = 0; k < 5; ++k) orow[8 + k] = (float)a3[k] * omt + (float)b3[k] * t;
        }
        __syncthreads();

        // Coalesced transpose write-out: ne*13 floats per table (div by 4).
        int totf = ne * R_CNT;                       // 3328 or 1664
        size_t obase = (size_t)ebase * R_CNT;
        for (int f0 = tid * 4; f0 < totf; f0 += 256 * 4) {
            float ph[4], po[4];
            #pragma unroll
            for (int k = 0; k < 4; ++k) {
                int f = f0 + k;
                int ee = f / 13;
                int rr = f - ee * 13;
                ph[k] = shh[ee * SH_STRIDE + rr];
                po[k] = sho[ee * SH_STRIDE + rr];
            }
            v4f qh = { ph[0], ph[1], ph[2], ph[3] };
            v4f qo = { po[0], po[1], po[2], po[3] };
            __builtin_nontemporal_store(qh, (v4f*)(out + obase + f0));
            __builtin_nontemporal_store(qo, (v4f*)(out + OUT_OVL_OFF + obase + f0));
        }
    } else {
        int n = (int)(blockIdx.x - EDGE_BLOCKS) * 256 + threadIdx.x;
        if (n < N_CNT) {
            int t = atom_type[n];
            v4f v = { onsite[t * OE_CNT + 0],
                      onsite[t * OE_CNT + 1],
                      onsite[t * OE_CNT + 2],
                      onsite[t * OE_CNT + 3] };
            __builtin_nontemporal_store(v, (v4f*)(out + OUT_NODE_OFF + (size_t)n * OE_CNT));
        }
    }
}

// Fallback (round-1 style, full fp32) if workspace is too small.
__global__ __launch_bounds__(256) void dftbsk_fallback(
    const float* __restrict__ rij,
    const int*   __restrict__ edge_type,
    const int*   __restrict__ atom_type,
    const float* __restrict__ xx,
    const float* __restrict__ hopping,
    const float* __restrict__ overlap,
    const float* __restrict__ onsite,
    float*       __restrict__ out)
{
    __shared__ float sxx[G_CNT];
    for (int i = threadIdx.x; i < G_CNT; i += blockDim.x) sxx[i] = xx[i];
    __syncthreads();

    long long gid = (long long)blockIdx.x * blockDim.x + threadIdx.x;
    if (gid < E_CNT) {
        int e = (int)gid;
        float r = rij[e];
        int b = edge_type[e];
        const float inv_dx = (float)(G_CNT - 1) / 5.0f;
        int idx = (int)floorf((r - 1.0f) * inv_dx);
        idx = max(0, min(G_CNT - 2, idx));
        while (idx > 0 && r < sxx[idx]) --idx;
        while (idx < G_CNT - 2 && r >= sxx[idx + 1]) ++idx;
        float x0 = sxx[idx], x1 = sxx[idx + 1];
        float t = (r - x0) / (x1 - x0);
        float omt = 1.0f - t;
        const float* hb = hopping + (size_t)b * (R_CNT * G_CNT) + idx;
        const float* ob = overlap + (size_t)b * (R_CNT * G_CNT) + idx;
        float* outh = out + (size_t)e * R_CNT;
        float* outo = out + OUT_OVL_OFF + (size_t)e * R_CNT;
        #pragma unroll
        for (int rr = 0; rr < R_CNT; ++rr)
            outh[rr] = hb[rr * G_CNT] * omt + hb[rr * G_CNT + 1] * t;
        #pragma unroll
        for (int rr = 0; rr < R_CNT; ++rr)
            outo[rr] = ob[rr * G_CNT] * omt + ob[rr * G_CNT + 1] * t;
    } else if (gid < (long long)E_CNT + N_CNT) {
        int n = (int)(gid - E_CNT);
        int t = atom_type[n];
        float4 v;
        v.x = onsite[t * OE_CNT + 0];
        v.y = onsite[t * OE_CNT + 1];
        v.z = onsite[t * OE_CNT + 2];
        v.w = onsite[t * OE_CNT + 3];
        *(float4*)(out + OUT_NODE_OFF + (size_t)n * OE_CNT) = v;
    }
}

extern "C" void kernel_launch(void* const* d_in, const int* in_sizes, int n_in,
                              void* d_out, int out_size, void* d_ws, size_t ws_size,
                              hipStream_t stream) {
    const float* rij        = (const float*)d_in[0];
    const int*   edge_type  = (const int*)d_in[1];
    const int*   atom_type  = (const int*)d_in[2];
    const float* xx         = (const float*)d_in[3];
    const float* hopping    = (const float*)d_in[4];
    const float* overlap    = (const float*)d_in[5];
    const float* onsite     = (const float*)d_in[6];
    float* out = (float*)d_out;

    if (ws_size >= P_BYTES) {
        _Float16* P = (_Float16*)d_ws;
        repack_h16_kernel<<<(B_CNT * G_CNT) / 256, 256, 0, stream>>>(
            hopping, overlap, P);
        sk16_mlp_kernel<<<EDGE_BLOCKS + NODE_BLOCKS, 256, 0, stream>>>(
            rij, edge_type, P, atom_type, onsite, out);
    } else {
        const long long total = (long long)E_CNT + N_CNT;
        const int grid = (int)((total + 255) / 256);
        dftbsk_fallback<<<grid, 256, 0, stream>>>(rij, edge_type, atom_type, xx,
                                                  hopping, overlap, onsite, out);
    }
}